// Round 5
// baseline (15562.119 us; speedup 1.0000x reference)
//
#include <hip/hip_runtime.h>

// Problem constants
#define TT 256
#define BB 256
#define EE 512
#define HH 1024
#define G4 4096
#define KTOT 1536
#define NBLK 256
#define WSTRIDE 1032   // LDS row stride (shorts) for 1024-col W_hh rows

typedef __attribute__((ext_vector_type(8))) short short8;
typedef __attribute__((ext_vector_type(4))) float f32x4;

__device__ __forceinline__ short f2bf(float f) {
    unsigned u; __builtin_memcpy(&u, &f, 4);
    unsigned r = (u + 0x7FFFu + ((u >> 16) & 1u)) >> 16;   // RNE
    return (short)(unsigned short)r;
}
__device__ __forceinline__ float bf2f(short s) {
    unsigned u = ((unsigned)(unsigned short)s) << 16;
    float f; __builtin_memcpy(&f, &u, 4);
    return f;
}
__device__ __forceinline__ float sigf(float x) { return 1.f / (1.f + __expf(-x)); }

// ---------------------------------------------------------------------------
// Prep: w_cat[r][0:1024]=w_hh[r], w_cat[r][1024:1536]=w_ih[r] (bf16);
//       bias[r] = b_ih[r] + b_hh[r]
// ---------------------------------------------------------------------------
__global__ __launch_bounds__(256) void prep_kernel(
    const float* __restrict__ w_ih, const float* __restrict__ w_hh,
    const float* __restrict__ b_ih, const float* __restrict__ b_hh,
    short* __restrict__ w_cat, float* __restrict__ bias)
{
    int r = blockIdx.x;
    int tid = threadIdx.x;
    for (int c = tid; c < KTOT; c += 256) {
        float v = (c < HH) ? w_hh[(size_t)r * HH + c]
                           : w_ih[(size_t)r * EE + (c - HH)];
        w_cat[(size_t)r * KTOT + c] = f2bf(v);
    }
    if (tid == 0) bias[r] = b_ih[r] + b_hh[r];
}

// ---------------------------------------------------------------------------
// Gather + convert: x_bf[t][b][:] = bf16(emb[text[b][t]][:])
// ---------------------------------------------------------------------------
__global__ __launch_bounds__(256) void gather_kernel(
    const int* __restrict__ text, const float* __restrict__ emb,
    short* __restrict__ xbf)
{
    int row = blockIdx.x * 4 + (threadIdx.x >> 6);   // b*TT + t
    int b = row >> 8, t = row & 255;
    int lane = threadIdx.x & 63;
    int v = text[row];
    const float* src = emb + (size_t)v * EE + lane * 8;
    float4 f0 = *(const float4*)src;
    float4 f1 = *(const float4*)(src + 4);
    float fv[8];
    *(float4*)&fv[0] = f0; *(float4*)&fv[4] = f1;
    short8 s;
    #pragma unroll
    for (int i = 0; i < 8; ++i) s[i] = f2bf(fv[i]);
    *(short8*)(xbf + ((size_t)t * BB + b) * EE + lane * 8) = s;
}

// ---------------------------------------------------------------------------
// Persistent LSTM, all 256 steps. 256 blocks x 1024 thr (16 waves), 1 blk/CU.
// 4 independent batch groups of 64 blocks; group gid owns batch rows
// [64*gid, 64*gid+64); blocks within a group = the 64 j-tiles. Group-local
// barrier: relaxed add + relaxed spin (periodic acquire-load backstop),
// ONE release fence before arrival, ONE acquire fence after exit.
// Wave (usub = wid&1, ksl = wid>>1): computes cols [usub*32, usub*32+32)
// (gates 2*usub, 2*usub+1) for K-slice ksl (h: 128, x: 64). W_hh slice in
// LDS (132 KB, loaded once); W_ih fragments in REGISTERS (t-invariant).
// K-slice partials reduced via LDS atomicAdd into Gt[64][66]. c in regs.
// x-part MFMAs issued BEFORE the barrier poll (overlap with barrier wait).
// ---------------------------------------------------------------------------
__global__ __launch_bounds__(1024, 4) void lstm_persist(
    const short* __restrict__ w_cat,   // [4096][1536] bf16
    const float* __restrict__ bias,    // [4096]
    const short* __restrict__ xbf,     // [T][B][E] bf16
    short* __restrict__ hbuf0,         // [B][H] bf16
    short* __restrict__ hbuf1,         // [B][H] bf16
    unsigned* __restrict__ bar)        // 4 group counters, 128 B apart
{
    __shared__ short Wl[64][WSTRIDE];  // 132096 B: 64 W_hh rows x 1024
    __shared__ float Gt[64][66];       // 16896 B: gate accumulators

    const int tid  = threadIdx.x;
    const int wid  = tid >> 6;
    const int lane = tid & 63;
    const int usub = wid & 1;          // column half (gates 2u, 2u+1)
    const int ksl  = wid >> 1;         // K-slice 0..7
    const int n    = lane & 15;
    const int q    = lane >> 4;

    const int bid = blockIdx.x;
    const int gid = bid >> 6;          // batch group 0..3
    const int j0  = (bid & 63) * 16;   // j-tile
    const int b0  = gid * 64;

    // ---- Load W_hh slice into LDS (once). LDS row r <-> W row (r>>4)*H + j0 + (r&15)
    {
        const int r  = tid >> 4;           // 0..63
        const int c0 = tid & 15;
        const short* src = w_cat + (size_t)((r >> 4) * HH + j0 + (r & 15)) * KTOT;
        #pragma unroll
        for (int i = 0; i < 8; ++i) {
            int c = (c0 + 16 * i) * 8;     // 0..1016, +8 <= 1024 <= WSTRIDE-8
            *(short8*)&Wl[r][c] = *(const short8*)(src + c);
        }
    }

    // ---- t-invariant W_ih fragments in registers (x-part B operand)
    // bf0: W row 2*usub*H + j0 + n ; bf1: (2*usub+1)*H + j0 + n ; cols HH + ksl*64 + kc*32 + q*8
    const short* wx0 = w_cat + (size_t)((2 * usub) * HH + j0 + n) * KTOT + HH + ksl * 64 + q * 8;
    const short* wx1 = w_cat + (size_t)((2 * usub + 1) * HH + j0 + n) * KTOT + HH + ksl * 64 + q * 8;
    const short8 wihf[2][2] = {
        { *(const short8*)(wx0), *(const short8*)(wx0 + 32) },
        { *(const short8*)(wx1), *(const short8*)(wx1 + 32) } };

    // ---- Per-thread epilogue cell (cb, cj); c-state in register
    const int cb = tid >> 4;           // batch row in tile 0..63
    const int cj = tid & 15;           // j within tile 0..15
    float creg = 0.f;
    const float bi  = bias[j0 + cj];
    const float bff = bias[HH + j0 + cj];
    const float bg  = bias[2 * HH + j0 + cj];
    const float bo  = bias[3 * HH + j0 + cj];
    short* hst0 = hbuf0 + (size_t)(b0 + cb) * HH + j0 + cj;
    short* hst1 = hbuf1 + (size_t)(b0 + cb) * HH + j0 + cj;

    for (int i = tid; i < 64 * 66; i += 1024) ((float*)Gt)[i] = 0.f;

    unsigned* mybar = bar + gid * 32;
    __syncthreads();   // Wl + Gt ready

    for (int t = 0; t < TT; ++t) {
        f32x4 acc[2][4];
        #pragma unroll
        for (int a = 0; a < 2; ++a)
            #pragma unroll
            for (int m = 0; m < 4; ++m) acc[a][m] = (f32x4){0.f, 0.f, 0.f, 0.f};

        // ---- x-part (independent of h) BEFORE the barrier poll
        const short* ax = xbf + ((size_t)t * BB + b0 + n) * EE + ksl * 64 + q * 8;
        #pragma unroll
        for (int kc = 0; kc < 2; ++kc) {
            #pragma unroll
            for (int mt = 0; mt < 4; ++mt) {
                short8 af = *(const short8*)(ax + (size_t)mt * 16 * EE + kc * 32);
                acc[0][mt] = __builtin_amdgcn_mfma_f32_16x16x32_bf16(af, wihf[0][kc], acc[0][mt], 0, 0, 0);
                acc[1][mt] = __builtin_amdgcn_mfma_f32_16x16x32_bf16(af, wihf[1][kc], acc[1][mt], 0, 0, 0);
            }
        }

        // ---- Group barrier wait: everyone finished step t-1 (h(t-1) visible)
        if (tid == 0 && t > 0) {
            const unsigned target = 64u * (unsigned)t;
            long guard = 0;
            while (__hip_atomic_load(mybar, __ATOMIC_RELAXED, __HIP_MEMORY_SCOPE_AGENT) < target) {
                if ((++guard & 255) == 0) {
                    // coherence backstop: acquire load forces refetch
                    if (__hip_atomic_load(mybar, __ATOMIC_ACQUIRE, __HIP_MEMORY_SCOPE_AGENT) >= target) break;
                    __builtin_amdgcn_s_sleep(2);
                }
                if (guard > (1L << 24)) break;   // hang-breaker
            }
            __builtin_amdgcn_fence(__ATOMIC_ACQUIRE, "agent");   // inv once
        }
        __syncthreads();

        // ---- h-part from LDS Wl (B) and global h (A)
        if (t > 0) {
            const short* hin = (t & 1) ? hbuf1 : hbuf0;
            const short* ah = hin + (size_t)(b0 + n) * HH + ksl * 128 + q * 8;
            #pragma unroll
            for (int kc = 0; kc < 4; ++kc) {
                const int col = ksl * 128 + kc * 32 + q * 8;
                short8 bf0 = *(const short8*)&Wl[usub * 32 + n][col];
                short8 bf1 = *(const short8*)&Wl[usub * 32 + 16 + n][col];
                #pragma unroll
                for (int mt = 0; mt < 4; ++mt) {
                    short8 af = *(const short8*)(ah + (size_t)mt * 16 * HH + kc * 32);
                    acc[0][mt] = __builtin_amdgcn_mfma_f32_16x16x32_bf16(af, bf0, acc[0][mt], 0, 0, 0);
                    acc[1][mt] = __builtin_amdgcn_mfma_f32_16x16x32_bf16(af, bf1, acc[1][mt], 0, 0, 0);
                }
            }
        }

        // ---- Reduce K-slice partials into Gt (LDS atomics)
        #pragma unroll
        for (int ut = 0; ut < 2; ++ut)
            #pragma unroll
            for (int mt = 0; mt < 4; ++mt)
                #pragma unroll
                for (int r = 0; r < 4; ++r)
                    atomicAdd(&Gt[mt * 16 + q * 4 + r][usub * 32 + ut * 16 + n],
                              acc[ut][mt][r]);
        __syncthreads();

        // ---- Epilogue: cell update; re-zero own Gt cells for next step
        float ip = Gt[cb][cj]      + bi;
        float fp = Gt[cb][16 + cj] + bff;
        float gp = Gt[cb][32 + cj] + bg;
        float op = Gt[cb][48 + cj] + bo;
        float cn = sigf(fp) * creg + sigf(ip) * tanhf(gp);
        creg = cn;
        float hn = sigf(op) * tanhf(cn);
        *((t & 1) ? hst0 : hst1) = f2bf(hn);
        Gt[cb][cj] = 0.f; Gt[cb][16 + cj] = 0.f;
        Gt[cb][32 + cj] = 0.f; Gt[cb][48 + cj] = 0.f;

        // ---- Arrive: h(t) stores drained (syncthreads), one release fence
        __syncthreads();
        if (tid == 0) {
            __builtin_amdgcn_fence(__ATOMIC_RELEASE, "agent");   // wbl2 once
            __hip_atomic_fetch_add(mybar, 1u, __ATOMIC_RELAXED, __HIP_MEMORY_SCOPE_AGENT);
        }
    }
}

// ---------------------------------------------------------------------------
// FC head: out[b] = sigmoid(dot(h[b], fc_w) + fc_b)
// ---------------------------------------------------------------------------
__global__ __launch_bounds__(256) void fc_kernel(
    const short* __restrict__ hbuf, const float* __restrict__ fc_w,
    const float* __restrict__ fc_b, float* __restrict__ out)
{
    __shared__ float red[4];
    int b = blockIdx.x;
    int tid = threadIdx.x;
    float s = 0.f;
    for (int k = tid; k < HH; k += 256)
        s += bf2f(hbuf[(size_t)b * HH + k]) * fc_w[k];
    #pragma unroll
    for (int off = 32; off > 0; off >>= 1) s += __shfl_down(s, off);
    if ((tid & 63) == 0) red[tid >> 6] = s;
    __syncthreads();
    if (tid == 0) {
        float tot = red[0] + red[1] + red[2] + red[3] + fc_b[0];
        out[b] = 1.f / (1.f + __expf(-tot));
    }
}

// ---------------------------------------------------------------------------
// Workspace layout (bytes):
//   w_cat @ 0           : 12,582,912
//   bias  @ 12,582,912  :     16,384
//   xbf   @ 12,599,296  : 67,108,864
//   hbuf0 @ 79,708,160  :    524,288
//   hbuf1 @ 80,232,448  :    524,288
//   bar   @ 80,756,736  :        512  (4 counters, 128 B apart)
// ---------------------------------------------------------------------------
extern "C" void kernel_launch(void* const* d_in, const int* in_sizes, int n_in,
                              void* d_out, int out_size, void* d_ws, size_t ws_size,
                              hipStream_t stream) {
    const int*   text = (const int*)d_in[0];
    const float* emb  = (const float*)d_in[1];
    const float* w_ih = (const float*)d_in[2];
    const float* w_hh = (const float*)d_in[3];
    const float* b_ih = (const float*)d_in[4];
    const float* b_hh = (const float*)d_in[5];
    const float* fc_w = (const float*)d_in[6];
    const float* fc_b = (const float*)d_in[7];
    float* out = (float*)d_out;

    char* ws = (char*)d_ws;
    short*    w_cat = (short*)(ws);
    float*    bias  = (float*)(ws + 12582912);
    short*    xbf   = (short*)(ws + 12599296);
    short*    hbuf0 = (short*)(ws + 79708160);
    short*    hbuf1 = (short*)(ws + 80232448);
    unsigned* bar   = (unsigned*)(ws + 80756736);

    hipMemsetAsync(bar, 0, 512, stream);
    gather_kernel<<<dim3(BB * TT / 4), dim3(256), 0, stream>>>(text, emb, xbf);
    prep_kernel<<<dim3(G4), dim3(256), 0, stream>>>(w_ih, w_hh, b_ih, b_hh, w_cat, bias);

    lstm_persist<<<dim3(NBLK), dim3(1024), 0, stream>>>(
        w_cat, bias, xbf, hbuf0, hbuf1, bar);

    fc_kernel<<<dim3(BB), dim3(256), 0, stream>>>(hbuf0, fc_w, fc_b, out);
}

// Round 6
// 14443.759 us; speedup vs baseline: 1.0774x; 1.0774x over previous
//
#include <hip/hip_runtime.h>

// Problem constants
#define TT 256
#define BB 256
#define EE 512
#define HH 1024
#define G4 4096
#define KTOT 1536
#define NBLK 256
#define WSTRIDE 1032   // LDS row stride (shorts) for 1024-col W_hh rows

typedef __attribute__((ext_vector_type(8))) short short8;
typedef __attribute__((ext_vector_type(4))) float f32x4;

__device__ __forceinline__ short f2bf(float f) {
    unsigned u; __builtin_memcpy(&u, &f, 4);
    unsigned r = (u + 0x7FFFu + ((u >> 16) & 1u)) >> 16;   // RNE
    return (short)(unsigned short)r;
}
__device__ __forceinline__ float bf2f(short s) {
    unsigned u = ((unsigned)(unsigned short)s) << 16;
    float f; __builtin_memcpy(&f, &u, 4);
    return f;
}
__device__ __forceinline__ float sigf(float x) { return 1.f / (1.f + __expf(-x)); }

// ---------------------------------------------------------------------------
// Prep: w_cat[r][0:1024]=w_hh[r], w_cat[r][1024:1536]=w_ih[r] (bf16);
//       bias[r] = b_ih[r] + b_hh[r]
// ---------------------------------------------------------------------------
__global__ __launch_bounds__(256) void prep_kernel(
    const float* __restrict__ w_ih, const float* __restrict__ w_hh,
    const float* __restrict__ b_ih, const float* __restrict__ b_hh,
    short* __restrict__ w_cat, float* __restrict__ bias)
{
    int r = blockIdx.x;
    int tid = threadIdx.x;
    for (int c = tid; c < KTOT; c += 256) {
        float v = (c < HH) ? w_hh[(size_t)r * HH + c]
                           : w_ih[(size_t)r * EE + (c - HH)];
        w_cat[(size_t)r * KTOT + c] = f2bf(v);
    }
    if (tid == 0) bias[r] = b_ih[r] + b_hh[r];
}

// ---------------------------------------------------------------------------
// Gather + convert: x_bf[t][b][:] = bf16(emb[text[b][t]][:])
// ---------------------------------------------------------------------------
__global__ __launch_bounds__(256) void gather_kernel(
    const int* __restrict__ text, const float* __restrict__ emb,
    short* __restrict__ xbf)
{
    int row = blockIdx.x * 4 + (threadIdx.x >> 6);   // b*TT + t
    int b = row >> 8, t = row & 255;
    int lane = threadIdx.x & 63;
    int v = text[row];
    const float* src = emb + (size_t)v * EE + lane * 8;
    float4 f0 = *(const float4*)src;
    float4 f1 = *(const float4*)(src + 4);
    float fv[8];
    *(float4*)&fv[0] = f0; *(float4*)&fv[4] = f1;
    short8 s;
    #pragma unroll
    for (int i = 0; i < 8; ++i) s[i] = f2bf(fv[i]);
    *(short8*)(xbf + ((size_t)t * BB + b) * EE + lane * 8) = s;
}

// ---------------------------------------------------------------------------
// Persistent LSTM, all 256 steps, 256 blocks x 1024 thr (16 waves), 1 blk/CU.
// 4 independent batch groups of 64 blocks (group gid owns batch rows
// [64*gid,64*gid+64); block (bid&63) = j-tile).
// Sync design (no wbl2 EVER):
//   - h stores: system-scope write-through (packed 2xbf16 -> uint), so values
//     reach IF$ without any L2 writeback fence.
//   - arrival: ONE relaxed system-scope flag store (t+1) per block per step.
//   - wait: wave 0's 64 lanes poll the 64 group flags with relaxed
//     system-scope loads + __ballot (fresh every poll, no cache ops).
//   - ONE agent acquire fence (inv) per step after the wait; cheap because
//     nothing in the loop depends on L2 residency (W_hh in LDS, W_ih in
//     registers, bias in registers, x streamed fresh).
// Wave (usub = wid&1, ksl = wid>>1): cols [usub*32,+32) (gates 2u,2u+1),
// K-slice ksl (h:128, x:64). K-partials reduced via LDS atomicAdd into Gt
// (mt order staggered by ksl to cut same-address contention). c in regs.
// x-part MFMAs issued BEFORE the flag wait (overlap with barrier latency).
// ---------------------------------------------------------------------------
__global__ __launch_bounds__(1024, 4) void lstm_persist(
    const short* __restrict__ w_cat,   // [4096][1536] bf16
    const float* __restrict__ bias,    // [4096]
    const short* __restrict__ xbf,     // [T][B][E] bf16
    short* __restrict__ hbuf0,         // [B][H] bf16
    short* __restrict__ hbuf1,         // [B][H] bf16
    unsigned* __restrict__ flags)      // [4][64] per-block step flags (zeroed)
{
    __shared__ short Wl[64][WSTRIDE];  // 132096 B: 64 W_hh rows x 1024
    __shared__ float Gt[64][66];       // 16896 B: gate accumulators

    const int tid  = threadIdx.x;
    const int wid  = tid >> 6;
    const int lane = tid & 63;
    const int usub = wid & 1;          // column half (gates 2u, 2u+1)
    const int ksl  = wid >> 1;         // K-slice 0..7
    const int n    = lane & 15;
    const int q    = lane >> 4;

    const int bid = blockIdx.x;
    const int gid = bid >> 6;          // batch group 0..3
    const int jt  = bid & 63;          // j-tile index
    const int j0  = jt * 16;
    const int b0  = gid * 64;

    // ---- Load W_hh slice into LDS (once). LDS row r <-> W row (r>>4)*H+j0+(r&15)
    {
        const int r  = tid >> 4;           // 0..63
        const int c0 = tid & 15;
        const short* src = w_cat + (size_t)((r >> 4) * HH + j0 + (r & 15)) * KTOT;
        #pragma unroll
        for (int i = 0; i < 8; ++i) {
            int c = (c0 + 16 * i) * 8;     // 0..1016
            *(short8*)&Wl[r][c] = *(const short8*)(src + c);
        }
    }

    // ---- t-invariant W_ih fragments in registers (x-part B operand)
    const short* wx0 = w_cat + (size_t)((2 * usub) * HH + j0 + n) * KTOT + HH + ksl * 64 + q * 8;
    const short* wx1 = w_cat + (size_t)((2 * usub + 1) * HH + j0 + n) * KTOT + HH + ksl * 64 + q * 8;
    const short8 wihf[2][2] = {
        { *(const short8*)(wx0), *(const short8*)(wx0 + 32) },
        { *(const short8*)(wx1), *(const short8*)(wx1 + 32) } };

    // ---- Epilogue cell pair: tid<512 -> (cb, j-pair cjp); c-state 2 regs
    const int cb  = tid >> 3;          // 0..63  (valid for tid<512)
    const int cjp = tid & 7;           // j-pair 0..7
    const int ja  = 2 * cjp, jb = ja + 1;
    float c0reg = 0.f, c1reg = 0.f;
    float bi0 = 0, bi1 = 0, bf0_ = 0, bf1_ = 0, bg0 = 0, bg1 = 0, bo0 = 0, bo1 = 0;
    unsigned* hst0 = nullptr; unsigned* hst1 = nullptr;
    if (tid < 512) {
        bi0 = bias[j0 + ja];            bi1 = bias[j0 + jb];
        bf0_ = bias[HH + j0 + ja];      bf1_ = bias[HH + j0 + jb];
        bg0 = bias[2 * HH + j0 + ja];   bg1 = bias[2 * HH + j0 + jb];
        bo0 = bias[3 * HH + j0 + ja];   bo1 = bias[3 * HH + j0 + jb];
        hst0 = (unsigned*)(hbuf0 + (size_t)(b0 + cb) * HH + j0 + ja);
        hst1 = (unsigned*)(hbuf1 + (size_t)(b0 + cb) * HH + j0 + ja);
    }

    for (int i = tid; i < 64 * 66; i += 1024) ((float*)Gt)[i] = 0.f;
    __syncthreads();   // Wl + Gt ready

    for (int t = 0; t < TT; ++t) {
        f32x4 acc[2][4];
        #pragma unroll
        for (int a = 0; a < 2; ++a)
            #pragma unroll
            for (int m = 0; m < 4; ++m) acc[a][m] = (f32x4){0.f, 0.f, 0.f, 0.f};

        // ---- x-part (independent of h) BEFORE the flag wait
        const short* ax = xbf + ((size_t)t * BB + b0 + n) * EE + ksl * 64 + q * 8;
        #pragma unroll
        for (int kc = 0; kc < 2; ++kc) {
            #pragma unroll
            for (int mt = 0; mt < 4; ++mt) {
                short8 af = *(const short8*)(ax + (size_t)mt * 16 * EE + kc * 32);
                acc[0][mt] = __builtin_amdgcn_mfma_f32_16x16x32_bf16(af, wihf[0][kc], acc[0][mt], 0, 0, 0);
                acc[1][mt] = __builtin_amdgcn_mfma_f32_16x16x32_bf16(af, wihf[1][kc], acc[1][mt], 0, 0, 0);
            }
        }

        // ---- Wait: all 64 group blocks finished step t-1
        if (t > 0 && wid == 0) {
            const unsigned* fl = flags + gid * 64 + lane;
            long guard = 0;
            for (;;) {
                unsigned v = __hip_atomic_load(fl, __ATOMIC_RELAXED, __HIP_MEMORY_SCOPE_SYSTEM);
                if (__ballot(v >= (unsigned)t) == ~0ull) break;
                if (++guard > (1L << 20)) break;   // hang-breaker
            }
            __builtin_amdgcn_fence(__ATOMIC_ACQUIRE, "agent");   // inv once/step
        }
        __syncthreads();

        // ---- h-part: A from global (IF$-fresh), B from LDS Wl
        if (t > 0) {
            const short* hin = (t & 1) ? hbuf1 : hbuf0;
            const short* ah = hin + (size_t)(b0 + n) * HH + ksl * 128 + q * 8;
            #pragma unroll
            for (int kc = 0; kc < 4; ++kc) {
                const int col = ksl * 128 + kc * 32 + q * 8;
                short8 bf0 = *(const short8*)&Wl[usub * 32 + n][col];
                short8 bf1 = *(const short8*)&Wl[usub * 32 + 16 + n][col];
                #pragma unroll
                for (int mt = 0; mt < 4; ++mt) {
                    short8 af = *(const short8*)(ah + (size_t)mt * 16 * HH + kc * 32);
                    acc[0][mt] = __builtin_amdgcn_mfma_f32_16x16x32_bf16(af, bf0, acc[0][mt], 0, 0, 0);
                    acc[1][mt] = __builtin_amdgcn_mfma_f32_16x16x32_bf16(af, bf1, acc[1][mt], 0, 0, 0);
                }
            }
        }

        // ---- Reduce K-slice partials into Gt (LDS atomics, mt staggered)
        #pragma unroll
        for (int ut = 0; ut < 2; ++ut)
            #pragma unroll
            for (int mi = 0; mi < 4; ++mi) {
                const int mt = (mi + ksl) & 3;
                #pragma unroll
                for (int r = 0; r < 4; ++r)
                    atomicAdd(&Gt[mt * 16 + q * 4 + r][usub * 32 + ut * 16 + n],
                              acc[ut][mt][r]);
            }
        __syncthreads();

        // ---- Epilogue (tid<512): 2 cells; h packed 2xbf16, system-scope store
        if (tid < 512) {
            float i0 = Gt[cb][ja]      + bi0, i1 = Gt[cb][jb]      + bi1;
            float f0 = Gt[cb][16 + ja] + bf0_, f1 = Gt[cb][16 + jb] + bf1_;
            float g0 = Gt[cb][32 + ja] + bg0, g1 = Gt[cb][32 + jb] + bg1;
            float o0 = Gt[cb][48 + ja] + bo0, o1 = Gt[cb][48 + jb] + bo1;
            float cn0 = sigf(f0) * c0reg + sigf(i0) * tanhf(g0);
            float cn1 = sigf(f1) * c1reg + sigf(i1) * tanhf(g1);
            c0reg = cn0; c1reg = cn1;
            float h0 = sigf(o0) * tanhf(cn0);
            float h1 = sigf(o1) * tanhf(cn1);
            unsigned hp = (unsigned)(unsigned short)f2bf(h0)
                        | ((unsigned)(unsigned short)f2bf(h1) << 16);
            __hip_atomic_store((t & 1) ? hst0 : hst1, hp,
                               __ATOMIC_RELAXED, __HIP_MEMORY_SCOPE_SYSTEM);
            Gt[cb][ja] = 0.f; Gt[cb][jb] = 0.f;
            Gt[cb][16 + ja] = 0.f; Gt[cb][16 + jb] = 0.f;
            Gt[cb][32 + ja] = 0.f; Gt[cb][32 + jb] = 0.f;
            Gt[cb][48 + ja] = 0.f; Gt[cb][48 + jb] = 0.f;
        }

        // ---- Arrive: syncthreads drains sys-scope h stores (vmcnt), then flag
        __syncthreads();
        if (tid == 0)
            __hip_atomic_store(flags + gid * 64 + jt, (unsigned)(t + 1),
                               __ATOMIC_RELAXED, __HIP_MEMORY_SCOPE_SYSTEM);
    }
}

// ---------------------------------------------------------------------------
// FC head: out[b] = sigmoid(dot(h[b], fc_w) + fc_b)
// ---------------------------------------------------------------------------
__global__ __launch_bounds__(256) void fc_kernel(
    const short* __restrict__ hbuf, const float* __restrict__ fc_w,
    const float* __restrict__ fc_b, float* __restrict__ out)
{
    __shared__ float red[4];
    int b = blockIdx.x;
    int tid = threadIdx.x;
    float s = 0.f;
    for (int k = tid; k < HH; k += 256)
        s += bf2f(hbuf[(size_t)b * HH + k]) * fc_w[k];
    #pragma unroll
    for (int off = 32; off > 0; off >>= 1) s += __shfl_down(s, off);
    if ((tid & 63) == 0) red[tid >> 6] = s;
    __syncthreads();
    if (tid == 0) {
        float tot = red[0] + red[1] + red[2] + red[3] + fc_b[0];
        out[b] = 1.f / (1.f + __expf(-tot));
    }
}

// ---------------------------------------------------------------------------
// Workspace layout (bytes):
//   w_cat @ 0           : 12,582,912
//   bias  @ 12,582,912  :     16,384
//   xbf   @ 12,599,296  : 67,108,864
//   hbuf0 @ 79,708,160  :    524,288
//   hbuf1 @ 80,232,448  :    524,288
//   flags @ 80,756,736  :      4,096  (4 groups x 64 uints, zeroed each call)
// ---------------------------------------------------------------------------
extern "C" void kernel_launch(void* const* d_in, const int* in_sizes, int n_in,
                              void* d_out, int out_size, void* d_ws, size_t ws_size,
                              hipStream_t stream) {
    const int*   text = (const int*)d_in[0];
    const float* emb  = (const float*)d_in[1];
    const float* w_ih = (const float*)d_in[2];
    const float* w_hh = (const float*)d_in[3];
    const float* b_ih = (const float*)d_in[4];
    const float* b_hh = (const float*)d_in[5];
    const float* fc_w = (const float*)d_in[6];
    const float* fc_b = (const float*)d_in[7];
    float* out = (float*)d_out;

    char* ws = (char*)d_ws;
    short*    w_cat = (short*)(ws);
    float*    bias  = (float*)(ws + 12582912);
    short*    xbf   = (short*)(ws + 12599296);
    short*    hbuf0 = (short*)(ws + 79708160);
    short*    hbuf1 = (short*)(ws + 80232448);
    unsigned* flags = (unsigned*)(ws + 80756736);

    hipMemsetAsync(flags, 0, 4096, stream);
    gather_kernel<<<dim3(BB * TT / 4), dim3(256), 0, stream>>>(text, emb, xbf);
    prep_kernel<<<dim3(G4), dim3(256), 0, stream>>>(w_ih, w_hh, b_ih, b_hh, w_cat, bias);

    lstm_persist<<<dim3(NBLK), dim3(1024), 0, stream>>>(
        w_cat, bias, xbf, hbuf0, hbuf1, flags);

    fc_kernel<<<dim3(BB), dim3(256), 0, stream>>>(hbuf0, fc_w, fc_b, out);
}

// Round 7
// 14043.912 us; speedup vs baseline: 1.1081x; 1.0285x over previous
//
#include <hip/hip_runtime.h>

// Problem constants
#define TT 256
#define BB 256
#define EE 512
#define HH 1024
#define G4 4096
#define KTOT 1536
#define NBLK 256
#define WSTRIDE 1032          // LDS row stride (shorts) for 1024-col W_hh rows
#define HSLOT (BB * HH)       // elements per h ring slot (524288 B)

typedef __attribute__((ext_vector_type(8))) short short8;
typedef __attribute__((ext_vector_type(4))) float f32x4;

__device__ __forceinline__ short f2bf(float f) {
    unsigned u; __builtin_memcpy(&u, &f, 4);
    unsigned r = (u + 0x7FFFu + ((u >> 16) & 1u)) >> 16;   // RNE
    return (short)(unsigned short)r;
}
__device__ __forceinline__ float bf2f(short s) {
    unsigned u = ((unsigned)(unsigned short)s) << 16;
    float f; __builtin_memcpy(&f, &u, 4);
    return f;
}
__device__ __forceinline__ float sigf(float x) { return 1.f / (1.f + __expf(-x)); }

// ---------------------------------------------------------------------------
// Prep: w_cat[r][0:1024]=w_hh[r], w_cat[r][1024:1536]=w_ih[r] (bf16);
//       bias[r] = b_ih[r] + b_hh[r]
// ---------------------------------------------------------------------------
__global__ __launch_bounds__(256) void prep_kernel(
    const float* __restrict__ w_ih, const float* __restrict__ w_hh,
    const float* __restrict__ b_ih, const float* __restrict__ b_hh,
    short* __restrict__ w_cat, float* __restrict__ bias)
{
    int r = blockIdx.x;
    int tid = threadIdx.x;
    for (int c = tid; c < KTOT; c += 256) {
        float v = (c < HH) ? w_hh[(size_t)r * HH + c]
                           : w_ih[(size_t)r * EE + (c - HH)];
        w_cat[(size_t)r * KTOT + c] = f2bf(v);
    }
    if (tid == 0) bias[r] = b_ih[r] + b_hh[r];
}

// ---------------------------------------------------------------------------
// Gather + convert: x_bf[t][b][:] = bf16(emb[text[b][t]][:])
// ---------------------------------------------------------------------------
__global__ __launch_bounds__(256) void gather_kernel(
    const int* __restrict__ text, const float* __restrict__ emb,
    short* __restrict__ xbf)
{
    int row = blockIdx.x * 4 + (threadIdx.x >> 6);   // b*TT + t
    int b = row >> 8, t = row & 255;
    int lane = threadIdx.x & 63;
    int v = text[row];
    const float* src = emb + (size_t)v * EE + lane * 8;
    float4 f0 = *(const float4*)src;
    float4 f1 = *(const float4*)(src + 4);
    float fv[8];
    *(float4*)&fv[0] = f0; *(float4*)&fv[4] = f1;
    short8 s;
    #pragma unroll
    for (int i = 0; i < 8; ++i) s[i] = f2bf(fv[i]);
    *(short8*)(xbf + ((size_t)t * BB + b) * EE + lane * 8) = s;
}

// ---------------------------------------------------------------------------
// Persistent LSTM, all 256 steps, 256 blocks x 1024 thr (16 waves), 1 blk/CU.
// 4 independent batch groups of 64 blocks (group gid owns batch rows
// [64*gid,64*gid+64); block (bid&63) = j-tile).
//
// Sync design — NO per-step cache maintenance:
//   - h(t) is written to ring slot (t % R): consumer addresses are FRESH
//     (never previously cached) whenever R covers the reuse distance, so
//     plain cached loads are coherent with zero fences. h-stores are
//     system-scope write-through (land at the coherence point; drained by
//     the pre-barrier vmcnt wait before the flag store).
//   - arrival: one relaxed system-scope flag store (t+1) per block per step.
//   - wait: wave 0's 64 lanes poll the 64 group flags (sys-scope) + ballot.
//   - Only if R < TT+1 (small workspace): ONE clustered agent acquire fence
//     every R steps (all blocks at the same t%R==0), amortized.
// Wave (usub = wid&1, ksl = wid>>1): cols [usub*32,+32) (gates 2u,2u+1),
// K-slice ksl (h:128, x:64). W_hh slice in LDS (132 KB, loaded once);
// W_ih fragments in registers. K-partials reduced via LDS atomicAdd into
// Gt (mt order staggered by ksl). c-state in registers.
// x-part MFMAs issued BEFORE the flag wait (overlap with barrier latency).
// ---------------------------------------------------------------------------
__global__ __launch_bounds__(1024, 4) void lstm_persist(
    const short* __restrict__ w_cat,   // [4096][1536] bf16
    const float* __restrict__ bias,    // [4096]
    const short* __restrict__ xbf,     // [T][B][E] bf16
    short* __restrict__ hring,         // [R][B][H] bf16 ring
    unsigned* __restrict__ flags,      // [4][64] per-block step flags (zeroed)
    int R)                             // ring length (>= 2)
{
    __shared__ short Wl[64][WSTRIDE];  // 132096 B: 64 W_hh rows x 1024
    __shared__ float Gt[64][66];       // 16896 B: gate accumulators

    const int tid  = threadIdx.x;
    const int wid  = tid >> 6;
    const int lane = tid & 63;
    const int usub = wid & 1;          // column half (gates 2u, 2u+1)
    const int ksl  = wid >> 1;         // K-slice 0..7
    const int n    = lane & 15;
    const int q    = lane >> 4;

    const int bid = blockIdx.x;
    const int gid = bid >> 6;          // batch group 0..3
    const int jt  = bid & 63;          // j-tile index
    const int j0  = jt * 16;
    const int b0  = gid * 64;

    // ---- Load W_hh slice into LDS (once)
    {
        const int r  = tid >> 4;           // 0..63
        const int c0 = tid & 15;
        const short* src = w_cat + (size_t)((r >> 4) * HH + j0 + (r & 15)) * KTOT;
        #pragma unroll
        for (int i = 0; i < 8; ++i) {
            int c = (c0 + 16 * i) * 8;
            *(short8*)&Wl[r][c] = *(const short8*)(src + c);
        }
    }

    // ---- t-invariant W_ih fragments in registers (x-part B operand)
    const short* wx0 = w_cat + (size_t)((2 * usub) * HH + j0 + n) * KTOT + HH + ksl * 64 + q * 8;
    const short* wx1 = w_cat + (size_t)((2 * usub + 1) * HH + j0 + n) * KTOT + HH + ksl * 64 + q * 8;
    const short8 wihf[2][2] = {
        { *(const short8*)(wx0), *(const short8*)(wx0 + 32) },
        { *(const short8*)(wx1), *(const short8*)(wx1 + 32) } };

    // ---- Epilogue cell pair: tid<512 -> (cb, j-pair cjp); c-state 2 regs
    const int cb  = tid >> 3;          // 0..63  (valid for tid<512)
    const int cjp = tid & 7;           // j-pair 0..7
    const int ja  = 2 * cjp, jb = ja + 1;
    float c0reg = 0.f, c1reg = 0.f;
    float bi0 = 0, bi1 = 0, bf0_ = 0, bf1_ = 0, bg0 = 0, bg1 = 0, bo0 = 0, bo1 = 0;
    size_t hoff = 0;
    if (tid < 512) {
        bi0 = bias[j0 + ja];            bi1 = bias[j0 + jb];
        bf0_ = bias[HH + j0 + ja];      bf1_ = bias[HH + j0 + jb];
        bg0 = bias[2 * HH + j0 + ja];   bg1 = bias[2 * HH + j0 + jb];
        bo0 = bias[3 * HH + j0 + ja];   bo1 = bias[3 * HH + j0 + jb];
        hoff = (size_t)(b0 + cb) * HH + j0 + ja;
    }

    for (int i = tid; i < 64 * 66; i += 1024) ((float*)Gt)[i] = 0.f;
    __syncthreads();   // Wl + Gt ready

    int wslot = 0;                     // == t % R at top of iteration
    int rslot = 0;                     // previous wslot (slot holding h(t-1))

    for (int t = 0; t < TT; ++t) {
        f32x4 acc[2][4];
        #pragma unroll
        for (int a = 0; a < 2; ++a)
            #pragma unroll
            for (int m = 0; m < 4; ++m) acc[a][m] = (f32x4){0.f, 0.f, 0.f, 0.f};

        // ---- x-part (independent of h) BEFORE the flag wait
        const short* ax = xbf + ((size_t)t * BB + b0 + n) * EE + ksl * 64 + q * 8;
        #pragma unroll
        for (int kc = 0; kc < 2; ++kc) {
            #pragma unroll
            for (int mt = 0; mt < 4; ++mt) {
                short8 af = *(const short8*)(ax + (size_t)mt * 16 * EE + kc * 32);
                acc[0][mt] = __builtin_amdgcn_mfma_f32_16x16x32_bf16(af, wihf[0][kc], acc[0][mt], 0, 0, 0);
                acc[1][mt] = __builtin_amdgcn_mfma_f32_16x16x32_bf16(af, wihf[1][kc], acc[1][mt], 0, 0, 0);
            }
        }

        // ---- Wait: all 64 group blocks finished step t-1 (h(t-1) landed)
        if (t > 0 && wid == 0) {
            const unsigned* fl = flags + gid * 64 + lane;
            long guard = 0;
            for (;;) {
                unsigned v = __hip_atomic_load(fl, __ATOMIC_RELAXED, __HIP_MEMORY_SCOPE_SYSTEM);
                if (__ballot(v >= (unsigned)t) == ~0ull) break;
                if (++guard > (1L << 22)) break;   // hang-breaker
            }
        }
        __syncthreads();

        // ---- Amortized coherence: only when the ring wraps (wslot==0, t>0)
        if (R < TT + 1 && t > 0 && wslot == 0)
            __builtin_amdgcn_fence(__ATOMIC_ACQUIRE, "agent");   // rare, clustered

        // ---- h-part: A from hring slot rslot (fresh addresses), B from LDS
        if (t > 0) {
            const short* ah = hring + (size_t)rslot * HSLOT
                            + (size_t)(b0 + n) * HH + ksl * 128 + q * 8;
            #pragma unroll
            for (int kc = 0; kc < 4; ++kc) {
                const int col = ksl * 128 + kc * 32 + q * 8;
                short8 bf0 = *(const short8*)&Wl[usub * 32 + n][col];
                short8 bf1 = *(const short8*)&Wl[usub * 32 + 16 + n][col];
                #pragma unroll
                for (int mt = 0; mt < 4; ++mt) {
                    short8 af = *(const short8*)(ah + (size_t)mt * 16 * HH + kc * 32);
                    acc[0][mt] = __builtin_amdgcn_mfma_f32_16x16x32_bf16(af, bf0, acc[0][mt], 0, 0, 0);
                    acc[1][mt] = __builtin_amdgcn_mfma_f32_16x16x32_bf16(af, bf1, acc[1][mt], 0, 0, 0);
                }
            }
        }

        // ---- Reduce K-slice partials into Gt (LDS atomics, mt staggered)
        #pragma unroll
        for (int ut = 0; ut < 2; ++ut)
            #pragma unroll
            for (int mi = 0; mi < 4; ++mi) {
                const int mt = (mi + ksl) & 3;
                #pragma unroll
                for (int r = 0; r < 4; ++r)
                    atomicAdd(&Gt[mt * 16 + q * 4 + r][usub * 32 + ut * 16 + n],
                              acc[ut][mt][r]);
            }
        __syncthreads();

        // ---- Epilogue (tid<512): 2 cells; h packed 2xbf16, sys-scope store
        if (tid < 512) {
            float i0 = Gt[cb][ja]      + bi0, i1 = Gt[cb][jb]      + bi1;
            float f0 = Gt[cb][16 + ja] + bf0_, f1 = Gt[cb][16 + jb] + bf1_;
            float g0 = Gt[cb][32 + ja] + bg0, g1 = Gt[cb][32 + jb] + bg1;
            float o0 = Gt[cb][48 + ja] + bo0, o1 = Gt[cb][48 + jb] + bo1;
            float cn0 = sigf(f0) * c0reg + sigf(i0) * tanhf(g0);
            float cn1 = sigf(f1) * c1reg + sigf(i1) * tanhf(g1);
            c0reg = cn0; c1reg = cn1;
            float h0 = sigf(o0) * tanhf(cn0);
            float h1 = sigf(o1) * tanhf(cn1);
            unsigned hp = (unsigned)(unsigned short)f2bf(h0)
                        | ((unsigned)(unsigned short)f2bf(h1) << 16);
            unsigned* hstw = (unsigned*)(hring + (size_t)wslot * HSLOT + hoff);
            __hip_atomic_store(hstw, hp, __ATOMIC_RELAXED, __HIP_MEMORY_SCOPE_SYSTEM);
            Gt[cb][ja] = 0.f; Gt[cb][jb] = 0.f;
            Gt[cb][16 + ja] = 0.f; Gt[cb][16 + jb] = 0.f;
            Gt[cb][32 + ja] = 0.f; Gt[cb][32 + jb] = 0.f;
            Gt[cb][48 + ja] = 0.f; Gt[cb][48 + jb] = 0.f;
        }

        // ---- Arrive: syncthreads drains sys-scope h stores (vmcnt), then flag
        __syncthreads();
        if (tid == 0)
            __hip_atomic_store(flags + gid * 64 + jt, (unsigned)(t + 1),
                               __ATOMIC_RELAXED, __HIP_MEMORY_SCOPE_SYSTEM);

        rslot = wslot;
        wslot = (wslot + 1 == R) ? 0 : wslot + 1;
    }
}

// ---------------------------------------------------------------------------
// FC head: out[b] = sigmoid(dot(h[b], fc_w) + fc_b)
// ---------------------------------------------------------------------------
__global__ __launch_bounds__(256) void fc_kernel(
    const short* __restrict__ hbuf, const float* __restrict__ fc_w,
    const float* __restrict__ fc_b, float* __restrict__ out)
{
    __shared__ float red[4];
    int b = blockIdx.x;
    int tid = threadIdx.x;
    float s = 0.f;
    for (int k = tid; k < HH; k += 256)
        s += bf2f(hbuf[(size_t)b * HH + k]) * fc_w[k];
    #pragma unroll
    for (int off = 32; off > 0; off >>= 1) s += __shfl_down(s, off);
    if ((tid & 63) == 0) red[tid >> 6] = s;
    __syncthreads();
    if (tid == 0) {
        float tot = red[0] + red[1] + red[2] + red[3] + fc_b[0];
        out[b] = 1.f / (1.f + __expf(-tot));
    }
}

// ---------------------------------------------------------------------------
// Workspace layout (bytes):
//   w_cat @ 0           : 12,582,912
//   bias  @ 12,582,912  :     16,384
//   flags @ 12,599,296  :      4,096
//   xbf   @ 12,603,392  : 67,108,864
//   hring @ 79,712,256  : R x 524,288   (R from ws_size; 257 = fence-free)
// ---------------------------------------------------------------------------
extern "C" void kernel_launch(void* const* d_in, const int* in_sizes, int n_in,
                              void* d_out, int out_size, void* d_ws, size_t ws_size,
                              hipStream_t stream) {
    const int*   text = (const int*)d_in[0];
    const float* emb  = (const float*)d_in[1];
    const float* w_ih = (const float*)d_in[2];
    const float* w_hh = (const float*)d_in[3];
    const float* b_ih = (const float*)d_in[4];
    const float* b_hh = (const float*)d_in[5];
    const float* fc_w = (const float*)d_in[6];
    const float* fc_b = (const float*)d_in[7];
    float* out = (float*)d_out;

    char* ws = (char*)d_ws;
    short*    w_cat = (short*)(ws);
    float*    bias  = (float*)(ws + 12582912);
    unsigned* flags = (unsigned*)(ws + 12599296);
    short*    xbf   = (short*)(ws + 12603392);
    short*    hring = (short*)(ws + 79712256);

    // Ring length from available workspace (257 -> no reuse -> no fences)
    long avail = (long)ws_size - 79712256L;
    int R = (int)(avail / 524288L);
    if (R > TT + 1) R = TT + 1;
    if (R < 2) R = 2;   // requires ws_size >= ~80.8 MB (validated in R5/R6)

    hipMemsetAsync(flags, 0, 4096, stream);
    gather_kernel<<<dim3(BB * TT / 4), dim3(256), 0, stream>>>(text, emb, xbf);
    prep_kernel<<<dim3(G4), dim3(256), 0, stream>>>(w_ih, w_hh, b_ih, b_hh, w_cat, bias);

    lstm_persist<<<dim3(NBLK), dim3(1024), 0, stream>>>(
        w_cat, bias, xbf, hring, flags, R);

    const int lastslot = (TT - 1) % R;
    fc_kernel<<<dim3(BB), dim3(256), 0, stream>>>(
        hring + (size_t)lastslot * HSLOT, fc_w, fc_b, out);
}